// Round 1
// baseline (297.039 us; speedup 1.0000x reference)
//
#include <hip/hip_runtime.h>

// Problem constants
#define BATCH   4
#define SEQ     4096
#define DMODEL  1024
#define HDIM    120
#define NPAD    128                    // HD padded to 128 (zero-filled) for clean K=4x32 MFMA loop
#define ROWS_TOTAL (BATCH * SEQ)       // 16384

typedef float f32x4 __attribute__((ext_vector_type(4)));
typedef short s16x8 __attribute__((ext_vector_type(8)));

static __device__ __forceinline__ unsigned short f2bf(float f) {
    unsigned u = __float_as_uint(f);
    u += 0x7FFFu + ((u >> 16) & 1u);   // round-to-nearest-even
    return (unsigned short)(u >> 16);
}

static __device__ __forceinline__ s16x8 pack8(const float* v) {
    s16x8 r;
#pragma unroll
    for (int i = 0; i < 8; ++i) r[i] = (short)f2bf(v[i]);
    return r;
}

// ---------------------------------------------------------------------------
// Kernel A: context = query @ Wq^T + bq, scaled by weight_tensor, L2-normalized
// rows. Output: ctx_n as bf16 [16384][128], cols 120..127 zero.
// Block: 256 threads (4 waves), 64 rows/block; each wave: 16 rows x 128 cols.
// bf16 MFMA 16x16x32, K-loop over 1024 in steps of 32, LDS-staged A/B tiles.
// ---------------------------------------------------------------------------
__global__ __launch_bounds__(256)
void ctx_norm_kernel(const float* __restrict__ query,
                     const float* __restrict__ Wq,
                     const float* __restrict__ bq,
                     const float* __restrict__ wt,
                     unsigned short* __restrict__ ctx)
{
    // row stride 40 (=32+8) bf16 elements: 80B rows -> only 2-way bank alias (free)
    __shared__ unsigned short lA[64 * 40];
    __shared__ unsigned short lB[128 * 40];

    const int tid  = threadIdx.x;
    const int lane = tid & 63;
    const int wv   = tid >> 6;          // wave 0..3 -> rows wv*16..+16
    const int l15  = lane & 15;
    const int l4   = lane >> 4;
    const int row0 = blockIdx.x * 64;

    f32x4 acc[8];
#pragma unroll
    for (int n = 0; n < 8; ++n) acc[n] = (f32x4){0.f, 0.f, 0.f, 0.f};

    const int ar = tid >> 2, aq = tid & 3;   // A staging: row 0..63, quarter 0..3 (8 floats)
    const int bn = tid >> 1, bh = tid & 1;   // B staging: row 0..127, half 0..1 (16 floats)

    for (int ks = 0; ks < 32; ++ks) {
        const int k0 = ks * 32;
        // stage A tile: query[row0+ar][k0 + aq*8 .. +8] -> bf16
        {
            const float* src = query + (size_t)(row0 + ar) * DMODEL + k0 + aq * 8;
            float tmp[8];
            *(f32x4*)(tmp)     = *(const f32x4*)(src);
            *(f32x4*)(tmp + 4) = *(const f32x4*)(src + 4);
            *(s16x8*)&lA[ar * 40 + aq * 8] = pack8(tmp);
        }
        // stage B tile: Wq[bn][k0 + bh*16 .. +16] -> bf16 (zero rows >= 120)
        {
            float tmp[16];
            if (bn < HDIM) {
                const float* src = Wq + (size_t)bn * DMODEL + k0 + bh * 16;
                *(f32x4*)(tmp)      = *(const f32x4*)(src);
                *(f32x4*)(tmp + 4)  = *(const f32x4*)(src + 4);
                *(f32x4*)(tmp + 8)  = *(const f32x4*)(src + 8);
                *(f32x4*)(tmp + 12) = *(const f32x4*)(src + 12);
            } else {
#pragma unroll
                for (int i = 0; i < 16; ++i) tmp[i] = 0.f;
            }
            *(s16x8*)&lB[bn * 40 + bh * 16]     = pack8(tmp);
            *(s16x8*)&lB[bn * 40 + bh * 16 + 8] = pack8(tmp + 8);
        }
        __syncthreads();

        const s16x8 a = *(const s16x8*)&lA[(wv * 16 + l15) * 40 + l4 * 8];
#pragma unroll
        for (int n = 0; n < 8; ++n) {
            const s16x8 bfr = *(const s16x8*)&lB[(n * 16 + l15) * 40 + l4 * 8];
            acc[n] = __builtin_amdgcn_mfma_f32_16x16x32_bf16(a, bfr, acc[n], 0, 0, 0);
        }
        __syncthreads();
    }

    // epilogue: (acc + bq)*wt, row L2-norm, store bf16
    // C/D layout: col = lane&15 (+16n), row = l4*4 + reg (+16*wv)
    float sumsq[4] = {0.f, 0.f, 0.f, 0.f};
#pragma unroll
    for (int n = 0; n < 8; ++n) {
        const int col = n * 16 + l15;
        const float bqv = (col < HDIM) ? bq[col] : 0.f;
        const float wvv = (col < HDIM) ? wt[col] : 0.f;   // wvv=0 zeroes pad cols
#pragma unroll
        for (int r = 0; r < 4; ++r) {
            const float v = (acc[n][r] + bqv) * wvv;
            acc[n][r] = v;
            sumsq[r] += v * v;
        }
    }
#pragma unroll
    for (int r = 0; r < 4; ++r) {
        float s = sumsq[r];
        s += __shfl_xor(s, 1);
        s += __shfl_xor(s, 2);
        s += __shfl_xor(s, 4);
        s += __shfl_xor(s, 8);
        sumsq[r] = 1.f / fmaxf(sqrtf(s), 1e-12f);   // 1/max(||x||, eps)
    }
#pragma unroll
    for (int r = 0; r < 4; ++r) {
        const size_t row = (size_t)(row0 + wv * 16 + l4 * 4 + r);
#pragma unroll
        for (int n = 0; n < 8; ++n) {
            ctx[row * NPAD + n * 16 + l15] = f2bf(acc[n][r] * sumsq[r]);
        }
    }
}

// ---------------------------------------------------------------------------
// Kernel B: scores = ctx_n @ ctx_n^T (per batch), softmax over cols, fp32 out.
// scores are cosines in [-1,1] -> skip max-subtraction: p = exp(s)/sum(exp(s)).
// Block: 1024 threads (16 waves = 4 row-groups x 4 col-groups), 64 rows/block,
// full 4096 cols. Two passes over col-tiles (recompute, K=128 is cheap; ctx per
// batch = 1MB -> L2-resident).
// ---------------------------------------------------------------------------
__global__ __launch_bounds__(1024)
void gram_softmax_kernel(const unsigned short* __restrict__ ctx,
                         float* __restrict__ out)
{
    __shared__ float lsum[64 * 4];      // [local row][col-group]

    const int tid  = threadIdx.x;
    const int lane = tid & 63;
    const int wv   = tid >> 6;          // 0..15
    const int rg   = wv >> 2;           // row-group 0..3 (16 rows each)
    const int cg   = wv & 3;            // col-group 0..3 (1024 cols each)
    const int l15  = lane & 15;
    const int l4   = lane >> 4;

    const int b    = blockIdx.x >> 6;
    const int rb   = blockIdx.x & 63;
    const int row0 = rb * 64 + rg * 16;                  // row within batch
    const unsigned short* cb = ctx + (size_t)b * SEQ * NPAD;

    // A fragments: this wave's 16 rows x K=128, kept in registers for both passes
    s16x8 afrag[4];
    {
        const unsigned short* ap = cb + (size_t)(row0 + l15) * NPAD + l4 * 8;
#pragma unroll
        for (int ks = 0; ks < 4; ++ks) afrag[ks] = *(const s16x8*)(ap + ks * 32);
    }

    const int col0 = cg * 1024;
    float rowsum[4] = {0.f, 0.f, 0.f, 0.f};

    // pass 1: row sums of exp(score)
    for (int t = 0; t < 64; ++t) {
        const unsigned short* bp = cb + (size_t)(col0 + t * 16 + l15) * NPAD + l4 * 8;
        f32x4 acc = (f32x4){0.f, 0.f, 0.f, 0.f};
#pragma unroll
        for (int ks = 0; ks < 4; ++ks) {
            const s16x8 bfr = *(const s16x8*)(bp + ks * 32);
            acc = __builtin_amdgcn_mfma_f32_16x16x32_bf16(afrag[ks], bfr, acc, 0, 0, 0);
        }
#pragma unroll
        for (int j = 0; j < 4; ++j) rowsum[j] += __expf(acc[j]);
    }
    // reduce across the 16 col-lanes of each row
#pragma unroll
    for (int j = 0; j < 4; ++j) {
        float s = rowsum[j];
        s += __shfl_xor(s, 1);
        s += __shfl_xor(s, 2);
        s += __shfl_xor(s, 4);
        s += __shfl_xor(s, 8);
        rowsum[j] = s;
    }
    // reduce across the 4 col-groups via LDS
    if (l15 == 0) {
#pragma unroll
        for (int j = 0; j < 4; ++j)
            lsum[(rg * 16 + l4 * 4 + j) * 4 + cg] = rowsum[j];
    }
    __syncthreads();
    float rinv[4];
#pragma unroll
    for (int j = 0; j < 4; ++j) {
        const int lr = rg * 16 + l4 * 4 + j;
        rinv[j] = 1.f / (lsum[lr * 4 + 0] + lsum[lr * 4 + 1] +
                         lsum[lr * 4 + 2] + lsum[lr * 4 + 3]);
    }

    // pass 2: recompute scores, write exp(s) * (1/rowsum)
    float* ob = out + ((size_t)b * SEQ + row0) * SEQ;
    for (int t = 0; t < 64; ++t) {
        const unsigned short* bp = cb + (size_t)(col0 + t * 16 + l15) * NPAD + l4 * 8;
        f32x4 acc = (f32x4){0.f, 0.f, 0.f, 0.f};
#pragma unroll
        for (int ks = 0; ks < 4; ++ks) {
            const s16x8 bfr = *(const s16x8*)(bp + ks * 32);
            acc = __builtin_amdgcn_mfma_f32_16x16x32_bf16(afrag[ks], bfr, acc, 0, 0, 0);
        }
        const int col = col0 + t * 16 + l15;
#pragma unroll
        for (int j = 0; j < 4; ++j) {
            const int r = l4 * 4 + j;
            ob[(size_t)r * SEQ + col] = __expf(acc[j]) * rinv[j];
        }
    }
}

extern "C" void kernel_launch(void* const* d_in, const int* in_sizes, int n_in,
                              void* d_out, int out_size, void* d_ws, size_t ws_size,
                              hipStream_t stream)
{
    const float* query = (const float*)d_in[0];
    // d_in[1] = key (unused by the forward)
    const float* Wq    = (const float*)d_in[2];
    const float* bq    = (const float*)d_in[3];
    const float* wt    = (const float*)d_in[4];
    float* out = (float*)d_out;
    unsigned short* ctx = (unsigned short*)d_ws;   // 16384*128*2 = 4 MiB scratch

    ctx_norm_kernel<<<dim3(ROWS_TOTAL / 64), dim3(256), 0, stream>>>(query, Wq, bq, wt, ctx);
    gram_softmax_kernel<<<dim3(BATCH * (SEQ / 64)), dim3(1024), 0, stream>>>(ctx, out);
}